// Round 13
// baseline (59.163 us; speedup 1.0000x reference)
//
#include <hip/hip_runtime.h>

#define BB 4
#define NN 512
#define NH 256
#define DD 64

typedef __attribute__((ext_vector_type(8))) short bf16x8;
typedef __attribute__((ext_vector_type(16))) float f32x16;
union BF8 { bf16x8 v; unsigned int u[4]; };

__device__ __forceinline__ float wred_sum(float v) {
  v += __shfl_xor(v, 32);
  v += __shfl_xor(v, 16);
  v += __shfl_xor(v, 8);
  v += __shfl_xor(v, 4);
  v += __shfl_xor(v, 2);
  v += __shfl_xor(v, 1);
  return v;
}

__device__ __forceinline__ float wred_max(float v) {
  v = fmaxf(v, __shfl_xor(v, 32));
  v = fmaxf(v, __shfl_xor(v, 16));
  v = fmaxf(v, __shfl_xor(v, 8));
  v = fmaxf(v, __shfl_xor(v, 4));
  v = fmaxf(v, __shfl_xor(v, 2));
  v = fmaxf(v, __shfl_xor(v, 1));
  return v;
}

__device__ __forceinline__ unsigned int cvtpk_bf16(float lo, float hi) {
  unsigned int r;
  asm("v_cvt_pk_bf16_f32 %0, %1, %2" : "=v"(r) : "v"(lo), "v"(hi));
  return r;
}

__device__ __forceinline__ float fast_tanh(float t) {
  t = fminf(15.f, fmaxf(-15.f, t));
  float z = __expf(2.f * t);
  return 1.f - 2.f * __builtin_amdgcn_rcpf(z + 1.f);
}

__device__ __forceinline__ float bflo(unsigned int u) { return __uint_as_float(u << 16); }
__device__ __forceinline__ float bfhi(unsigned int u) { return __uint_as_float(u & 0xffff0000u); }

// K1: x[b,n,:] = (n<256 ? x1@W_t1+b_t1 : x2@W_t2+b_t2)
__global__ __launch_bounds__(256)
void k1_build_x(const float* __restrict__ x1, const float* __restrict__ x2,
                const float* __restrict__ W_t1, const float* __restrict__ b_t1,
                const float* __restrict__ W_t2, const float* __restrict__ b_t2,
                float* __restrict__ X) {
  const int tid = threadIdx.x;
  const int lane = tid & 63;
  const int rq = tid >> 6;
  const int r = blockIdx.x * 4 + rq;
  const int b = r >> 9;
  const int n = r & 511;
  const float* src; const float* W; const float* bias;
  if (n < NH) { src = x1 + (b * NH + n) * DD;        W = W_t1; bias = b_t1; }
  else        { src = x2 + (b * NH + (n - NH)) * DD; W = W_t2; bias = b_t2; }
  const float4* s4 = reinterpret_cast<const float4*>(src);
  float t0 = 0.f, t1 = 0.f, t2 = 0.f, t3 = 0.f;
#pragma unroll
  for (int c = 0; c < 16; ++c) {
    const float4 v = s4[c];
    t0 = fmaf(v.x, W[(4 * c + 0) * DD + lane], t0);
    t1 = fmaf(v.y, W[(4 * c + 1) * DD + lane], t1);
    t2 = fmaf(v.z, W[(4 * c + 2) * DD + lane], t2);
    t3 = fmaf(v.w, W[(4 * c + 3) * DD + lane], t3);
  }
  X[r * DD + lane] = ((t0 + t1) + (t2 + t3)) + bias[lane];
}

// K_SC: symmetric-triangle scores -> scG (both mirror locations written).
// 512 thr = 8 waves; grid (128,4). Epilogue: balanced 13-VALU + 1-trans
// rational tanh (R10-proven poly, v_rcp division) -- loads trans AND valu
// pipes evenly instead of trans-heavy exp form.
__global__ __launch_bounds__(512, 1)
void k_sc(const float* __restrict__ X,
          const float* __restrict__ W_att, const float* __restrict__ b_att,
          const float* __restrict__ w11, const float* __restrict__ w22,
          const float* __restrict__ w12,
          float* __restrict__ scG) {
  const int b = blockIdx.y;
  const int bx = blockIdx.x;           // 0..127
  const int tid = threadIdx.x;
  const int lane = tid & 63;
  const int w = tid >> 6;              // 0..7
  const int l31 = lane & 31;
  const int half = lane >> 5;

  __shared__ __align__(16) float tblB[64];      // b_att, C-reg order
  __shared__ __align__(16) float tblW[4][64];   // wsel, C-reg order, per comb

  const float* __restrict__ Xb = X + b * NN * DD;
  float* __restrict__ scb = scG + b * NN * NN;

  if (tid < 64) {
    const int ot = tid >> 5, hf = (tid >> 4) & 1, r = tid & 15;
    const int o = ot * 32 + (r & 3) + 8 * (r >> 2) + 4 * hf;
    tblB[tid] = b_att[o];
  }
  if (tid >= 64 && tid < 320) {
    const int t = tid - 64;            // 0..255
    const int comb = t >> 6;           // it*2+jt
    const int idx = t & 63;
    const int ot = idx >> 5, hf = (idx >> 4) & 1, r = idx & 15;
    const int o = ot * 32 + (r & 3) + 8 * (r >> 2) + 4 * hf;
    const int it_ = comb >> 1, jt_ = comb & 1;
    const float* wsl = it_ ? (jt_ ? w22 : w12) : (jt_ ? w12 : w11);
    tblW[comb][idx] = wsl[o];
  }

  // W^T fragments in regs (32 VGPR, proven layout)
  BF8 Wp[2][4];
#pragma unroll
  for (int ot = 0; ot < 2; ++ot)
#pragma unroll
    for (int kt = 0; kt < 4; ++kt) {
      const int o = ot * 32 + l31;
#pragma unroll
      for (int p = 0; p < 4; ++p) {
        const int d0 = kt * 16 + half * 8 + 2 * p;
        Wp[ot][kt].u[p] = cvtpk_bf16(W_att[d0 * DD + o], W_att[(d0 + 1) * DD + o]);
      }
    }

  __syncthreads();

  // job list: strip A rows {2bx, 2bx+1}, chunks [bx>>4, 16); strip B rows
  // {510-2bx, 511-2bx}, chunks [(255-bx)>>4, 16). Total 17 chunks -> 34 jobs.
  const int cminA = bx >> 4;
  const int n32A = 16 - cminA;
  const int rB = 510 - 2 * bx;
  const int cminB = (255 - bx) >> 4;
  const int njobs = 2 * (n32A + (16 - cminB));   // = 34

#pragma unroll 1
  for (int t = w; t < njobs; t += 8) {
    int row, c32;
    if (t < 2 * n32A) { row = 2 * bx + (t & 1); c32 = cminA + (t >> 1); }
    else { const int tp = t - 2 * n32A; row = rB + (tp & 1); c32 = cminB + (tp >> 1); }
    const int j0 = c32 * 32;
    const int comb = ((row >= NH) ? 2 : 0) | ((j0 >= NH) ? 1 : 0);

    // load xi (row) and xj (j0+l31) slices, packed bf16 (proven pattern)
    BF8 Xi[4], Xj[4];
#pragma unroll
    for (int kt = 0; kt < 4; ++kt) {
      const float* bi = Xb + row * DD + kt * 16 + half * 8;
      const float4 a = *reinterpret_cast<const float4*>(bi);
      const float4 c = *reinterpret_cast<const float4*>(bi + 4);
      Xi[kt].u[0] = cvtpk_bf16(a.x, a.y);
      Xi[kt].u[1] = cvtpk_bf16(a.z, a.w);
      Xi[kt].u[2] = cvtpk_bf16(c.x, c.y);
      Xi[kt].u[3] = cvtpk_bf16(c.z, c.w);
      const float* bj = Xb + (j0 + l31) * DD + kt * 16 + half * 8;
      const float4 aj = *reinterpret_cast<const float4*>(bj);
      const float4 cj = *reinterpret_cast<const float4*>(bj + 4);
      Xj[kt].u[0] = cvtpk_bf16(aj.x, aj.y);
      Xj[kt].u[1] = cvtpk_bf16(aj.z, aj.w);
      Xj[kt].u[2] = cvtpk_bf16(cj.x, cj.y);
      Xj[kt].u[3] = cvtpk_bf16(cj.z, cj.w);
    }

    f32x16 C0 = {}, C1 = {};
#pragma unroll
    for (int kt = 0; kt < 4; ++kt) {
      BF8 Bi;
#pragma unroll
      for (int p = 0; p < 4; ++p)
        Bi.u[p] = cvtpk_bf16(bflo(Xi[kt].u[p]) * bflo(Xj[kt].u[p]),
                             bfhi(Xi[kt].u[p]) * bfhi(Xj[kt].u[p]));
      C0 = __builtin_amdgcn_mfma_f32_32x32x16_bf16(Wp[0][kt].v, Bi.v, C0, 0, 0, 0);
      C1 = __builtin_amdgcn_mfma_f32_32x32x16_bf16(Wp[1][kt].v, Bi.v, C1, 0, 0, 0);
    }

    // epilogue: rational tanh (13 VALU + 1 rcp per channel)
    // tanh(x) ~ x*(135135+17325f+378f^2+f^3) / (135135+62370f+3150f^2+28f^3)
    float p = 0.f;
    const int base = half * 16;
    const float* tw = tblW[comb];
#pragma unroll
    for (int r = 0; r < 16; ++r) {
      {
        float x = C0[r] + tblB[base + r];
        x = fminf(4.8f, fmaxf(-4.8f, x));
        const float f = x * x;
        const float nu = x * fmaf(f, fmaf(f, (f + 378.f), 17325.f), 135135.f);
        const float de = fmaf(f, fmaf(f, fmaf(f, 28.f, 3150.f), 62370.f), 135135.f);
        p = fmaf(tw[base + r] * nu, __builtin_amdgcn_rcpf(de), p);
      }
      {
        float x = C1[r] + tblB[32 + base + r];
        x = fminf(4.8f, fmaxf(-4.8f, x));
        const float f = x * x;
        const float nu = x * fmaf(f, fmaf(f, (f + 378.f), 17325.f), 135135.f);
        const float de = fmaf(f, fmaf(f, fmaf(f, 28.f, 3150.f), 62370.f), 135135.f);
        p = fmaf(tw[32 + base + r] * nu, __builtin_amdgcn_rcpf(de), p);
      }
    }
    p += __shfl_xor(p, 32);
    if (lane < 32) {
      const int j = j0 + l31;
      if (j >= row) {                     // single-writer ownership
        scb[row * NN + j] = p;
        if (j > row) scb[j * NN + row] = p;   // symmetric mirror
      }
    }
  }
}

// K_REST: softmax + agg + y(selu) + logits + master (R8/R12 passed verbatim).
__global__ __launch_bounds__(1024, 4)
void k_rest(const float* __restrict__ X, const float* __restrict__ scG,
            const float* __restrict__ W_attM, const float* __restrict__ b_attM,
            const float* __restrict__ wM,
            const float* __restrict__ W_pa, const float* __restrict__ b_pa,
            const float* __restrict__ W_po, const float* __restrict__ b_po,
            const float* __restrict__ gamma, const float* __restrict__ beta,
            float* __restrict__ master, float* __restrict__ logits,
            float* __restrict__ out) {
  const int b = blockIdx.y;
  const int i0 = blockIdx.x * 8;
  const int tid = threadIdx.x;
  const int lane = tid & 63;
  const int w = tid >> 6;        // 0..15

  __shared__ __align__(16) float Xlds[NN * DD];   // 128 KB
  __shared__ __align__(16) float scL[8 * NN];     // 16 KB
  __shared__ __align__(16) float red2[16][DD];    // 4 KB
  __shared__ __align__(16) float aggL[8][DD];     // 2 KB
  __shared__ __align__(16) float mastL[64];

  const float* __restrict__ Xb = X + b * NN * DD;

  // stage X[b] f32
  {
    const int c4 = (tid & 15) * 4;
    const int rh = tid >> 4;
#pragma unroll
    for (int it = 0; it < 8; ++it) {
      const int r = it * 64 + rh;
      *reinterpret_cast<float4*>(&Xlds[r * DD + c4]) =
          *reinterpret_cast<const float4*>(&Xb[r * DD + c4]);
    }
  }
  // stage scores
  {
    const int r8 = tid >> 7;
    const int c = (tid & 127) * 4;
    *reinterpret_cast<float4*>(&scL[r8 * NN + c]) =
        *reinterpret_cast<const float4*>(&scG[(b * NN + i0 + r8) * NN + c]);
  }
  __syncthreads();   // bar1

  // master mean
  {
    float s = 0.f;
    for (int r = w * 32; r < w * 32 + 32; ++r) s += Xlds[r * DD + lane];
    red2[w][lane] = s;
  }
  __syncthreads();   // bar2
  if (w == 0) {
    float s = 0.f;
#pragma unroll
    for (int k = 0; k < 16; ++k) s += red2[k][lane];
    s *= (1.f / 512.f);
    mastL[lane] = s;
    if (blockIdx.x == 0) master[b * DD + lane] = s;
  }

  // softmax: 2 waves per row
  const int row = w & 7, part = w >> 3;
  const int irow = i0 + row;
  float v[8];
#pragma unroll
  for (int k = 0; k < 8; ++k) v[k] = scL[row * NN + lane + 64 * k];
  __syncthreads();   // bar3b
  float mx = fmaxf(fmaxf(fmaxf(v[0], v[1]), fmaxf(v[2], v[3])),
                   fmaxf(fmaxf(v[4], v[5]), fmaxf(v[6], v[7])));
  mx = wred_max(mx);
  float ssum = 0.f;
#pragma unroll
  for (int k = 0; k < 8; ++k) { v[k] = __expf(v[k] - mx); ssum += v[k]; }
  ssum = wred_sum(ssum);
  const float inv = __builtin_amdgcn_rcpf(ssum);
#pragma unroll
  for (int k = 0; k < 4; ++k) {
    const int kk = part * 4 + k;
    scL[row * NN + lane + 64 * kk] = v[kk] * inv;
  }

  // agg partial over own j-half
  float a0 = 0.f, a1 = 0.f, a2 = 0.f, a3 = 0.f;
  const float* scr = &scL[row * NN + part * 256];
  const int xof = part * 256 * DD;
  for (int jj = 0; jj < 64; ++jj) {
    const float4 at = *reinterpret_cast<const float4*>(&scr[jj * 4]);
    a0 = fmaf(at.x, Xlds[xof + (jj * 4 + 0) * DD + lane], a0);
    a1 = fmaf(at.y, Xlds[xof + (jj * 4 + 1) * DD + lane], a1);
    a2 = fmaf(at.z, Xlds[xof + (jj * 4 + 2) * DD + lane], a2);
    a3 = fmaf(at.w, Xlds[xof + (jj * 4 + 3) * DD + lane], a3);
  }
  red2[w][lane] = (a0 + a1) + (a2 + a3);
  __syncthreads();   // bar4

  if (part == 0) {
    const float aggv = red2[w][lane] + red2[w + 8][lane];
    aggL[row][lane] = aggv;
    float y = b_pa[lane] + b_po[lane];
#pragma unroll 8
    for (int d = 0; d < DD; ++d) {
      y = fmaf(aggL[row][d], W_pa[d * DD + lane], y);
      y = fmaf(Xlds[irow * DD + d], W_po[d * DD + lane], y);
    }
    const float RSQ = 0.9999950000374997f;
    y = y * RSQ * gamma[lane] + beta[lane];
    const float SC_ = 1.0507009873554805f;
    const float AL = 1.6732632423543772f;
    y = (y > 0.f) ? (SC_ * y) : (SC_ * AL * (__expf(y) - 1.f));
    const int off = (irow < NH) ? ((b * NH + irow) * DD + lane)
                                : (BB * NH * DD + (b * NH + (irow - NH)) * DD + lane);
    out[off] = y;
  } else {
    float lg = b_attM[lane];
#pragma unroll 8
    for (int d = 0; d < DD; ++d)
      lg = fmaf(Xlds[irow * DD + d] * mastL[d], W_attM[d * DD + lane], lg);
    const float th = fast_tanh(lg);
    const float s = wred_sum(th * wM[lane]);
    if (lane == 0) logits[b * NN + irow] = s;
  }
}

// K4: softmax_n(logits) -> agg_m -> master_new (tail of out)
__global__ __launch_bounds__(256)
void k4_master_new(const float* __restrict__ X, const float* __restrict__ master,
                   const float* __restrict__ logits,
                   const float* __restrict__ W_paM, const float* __restrict__ b_paM,
                   const float* __restrict__ W_poM, const float* __restrict__ b_poM,
                   float* __restrict__ out) {
  const int b = blockIdx.x;
  const int tid = threadIdx.x;
  const int lane = tid & 63;
  const int q = tid >> 6;
  __shared__ float red[4][DD];
  __shared__ float r4[4];
  __shared__ float aggm_s[DD];
  __shared__ float mrow_s[DD];
  const float* lg = logits + b * NN;
  const float v0 = lg[tid];
  const float v1 = lg[tid + 256];
  float mx = wred_max(fmaxf(v0, v1));
  if (lane == 0) r4[q] = mx;
  __syncthreads();
  mx = fmaxf(fmaxf(r4[0], r4[1]), fmaxf(r4[2], r4[3]));
  float es = __expf(v0 - mx) + __expf(v1 - mx);
  es = wred_sum(es);
  __syncthreads();
  if (lane == 0) r4[q] = es;
  __syncthreads();
  const float S = r4[0] + r4[1] + r4[2] + r4[3];
  const float invS = 1.f / S;

  float acc = 0.f;
  for (int nn = q * 128; nn < q * 128 + 128; ++nn) {
    const float a = __expf(lg[nn] - mx);
    acc = fmaf(a, X[(b * NN + nn) * DD + lane], acc);
  }
  red[q][lane] = acc;
  __syncthreads();
  if (q == 0) {
    aggm_s[lane] =
        (red[0][lane] + red[1][lane] + red[2][lane] + red[3][lane]) * invS;
    mrow_s[lane] = master[b * DD + lane];
  }
  __syncthreads();
  float p = 0.f;
  for (int d = q * 16; d < q * 16 + 16; ++d) {
    p = fmaf(aggm_s[d], W_paM[d * DD + lane], p);
    p = fmaf(mrow_s[d], W_poM[d * DD + lane], p);
  }
  __syncthreads();
  red[q][lane] = p;
  __syncthreads();
  if (q == 0) {
    out[2 * BB * NH * DD + b * DD + lane] =
        red[0][lane] + red[1][lane] + red[2][lane] + red[3][lane] +
        b_paM[lane] + b_poM[lane];
  }
}

extern "C" void kernel_launch(void* const* d_in, const int* in_sizes, int n_in,
                              void* d_out, int out_size, void* d_ws, size_t ws_size,
                              hipStream_t stream) {
  const float* x1    = (const float*)d_in[0];
  const float* x2    = (const float*)d_in[1];
  const float* W_t1  = (const float*)d_in[2];
  const float* b_t1  = (const float*)d_in[3];
  const float* W_t2  = (const float*)d_in[4];
  const float* b_t2  = (const float*)d_in[5];
  const float* W_att = (const float*)d_in[6];
  const float* b_att = (const float*)d_in[7];
  const float* W_attM = (const float*)d_in[8];
  const float* b_attM = (const float*)d_in[9];
  const float* w11   = (const float*)d_in[10];
  const float* w22   = (const float*)d_in[11];
  const float* w12   = (const float*)d_in[12];
  const float* wM    = (const float*)d_in[13];
  const float* W_pa  = (const float*)d_in[14];
  const float* b_pa  = (const float*)d_in[15];
  const float* W_po  = (const float*)d_in[16];
  const float* b_po  = (const float*)d_in[17];
  const float* W_paM = (const float*)d_in[18];
  const float* b_paM = (const float*)d_in[19];
  const float* W_poM = (const float*)d_in[20];
  const float* b_poM = (const float*)d_in[21];
  const float* gamma = (const float*)d_in[22];
  const float* beta  = (const float*)d_in[23];

  float* ws     = (float*)d_ws;
  float* X      = ws;            // 131072 floats
  float* master = ws + 131072;   // 256
  float* logits = ws + 131328;   // 2048
  float* scG    = ws + 133376;   // 1048576 floats (4 MB)
  float* out    = (float*)d_out;

  k1_build_x<<<512, 256, 0, stream>>>(x1, x2, W_t1, b_t1, W_t2, b_t2, X);
  k_sc<<<dim3(128, 4), 512, 0, stream>>>(X, W_att, b_att, w11, w22, w12, scG);
  k_rest<<<dim3(64, 4), 1024, 0, stream>>>(X, scG, W_attM, b_attM, wM,
                                           W_pa, b_pa, W_po, b_po, gamma, beta,
                                           master, logits, out);
  k4_master_new<<<4, 256, 0, stream>>>(X, master, logits, W_paM, b_paM, W_poM, b_poM, out);
}

// Round 14
// 49.288 us; speedup vs baseline: 1.2004x; 1.2004x over previous
//
#include <hip/hip_runtime.h>

#define BB 4
#define NN 512
#define NH 256
#define DD 64

typedef __attribute__((ext_vector_type(8))) short bf16x8;
typedef __attribute__((ext_vector_type(16))) float f32x16;
union BF8 { bf16x8 v; unsigned int u[4]; };
union BF8Q { bf16x8 v; uint4 q; };

__device__ __forceinline__ float wred_sum(float v) {
  v += __shfl_xor(v, 32);
  v += __shfl_xor(v, 16);
  v += __shfl_xor(v, 8);
  v += __shfl_xor(v, 4);
  v += __shfl_xor(v, 2);
  v += __shfl_xor(v, 1);
  return v;
}

__device__ __forceinline__ float wred_max(float v) {
  v = fmaxf(v, __shfl_xor(v, 32));
  v = fmaxf(v, __shfl_xor(v, 16));
  v = fmaxf(v, __shfl_xor(v, 8));
  v = fmaxf(v, __shfl_xor(v, 4));
  v = fmaxf(v, __shfl_xor(v, 2));
  v = fmaxf(v, __shfl_xor(v, 1));
  return v;
}

__device__ __forceinline__ unsigned int cvtpk_bf16(float lo, float hi) {
  unsigned int r;
  asm("v_cvt_pk_bf16_f32 %0, %1, %2" : "=v"(r) : "v"(lo), "v"(hi));
  return r;
}

__device__ __forceinline__ float fast_exp2(float x) {
  float r;
  asm("v_exp_f32 %0, %1" : "=v"(r) : "v"(x));
  return r;
}

__device__ __forceinline__ float fast_tanh(float t) {
  t = fminf(15.f, fmaxf(-15.f, t));
  float z = __expf(2.f * t);
  return 1.f - 2.f * __builtin_amdgcn_rcpf(z + 1.f);
}

__device__ __forceinline__ float bflo(unsigned int u) { return __uint_as_float(u << 16); }
__device__ __forceinline__ float bfhi(unsigned int u) { return __uint_as_float(u & 0xffff0000u); }

// K1: x[b,n,:] = (n<256 ? x1@W_t1+b_t1 : x2@W_t2+b_t2); also bf16-packed Xbf.
__global__ __launch_bounds__(256)
void k1_build_x(const float* __restrict__ x1, const float* __restrict__ x2,
                const float* __restrict__ W_t1, const float* __restrict__ b_t1,
                const float* __restrict__ W_t2, const float* __restrict__ b_t2,
                float* __restrict__ X, unsigned int* __restrict__ XbfG) {
  const int tid = threadIdx.x;
  const int lane = tid & 63;
  const int rq = tid >> 6;
  const int r = blockIdx.x * 4 + rq;
  const int b = r >> 9;
  const int n = r & 511;
  const float* src; const float* W; const float* bias;
  if (n < NH) { src = x1 + (b * NH + n) * DD;        W = W_t1; bias = b_t1; }
  else        { src = x2 + (b * NH + (n - NH)) * DD; W = W_t2; bias = b_t2; }
  const float4* s4 = reinterpret_cast<const float4*>(src);
  float t0 = 0.f, t1 = 0.f, t2 = 0.f, t3 = 0.f;
#pragma unroll
  for (int c = 0; c < 16; ++c) {
    const float4 v = s4[c];
    t0 = fmaf(v.x, W[(4 * c + 0) * DD + lane], t0);
    t1 = fmaf(v.y, W[(4 * c + 1) * DD + lane], t1);
    t2 = fmaf(v.z, W[(4 * c + 2) * DD + lane], t2);
    t3 = fmaf(v.w, W[(4 * c + 3) * DD + lane], t3);
  }
  const float yv = ((t0 + t1) + (t2 + t3)) + bias[lane];
  X[r * DD + lane] = yv;
  const float nb = __shfl_down(yv, 1);      // partner d = lane+1 (same wave/row)
  if ((lane & 1) == 0) XbfG[r * 32 + (lane >> 1)] = cvtpk_bf16(yv, nb);
}

// K_SC: symmetric-triangle scores -> scG. 512 thr = 8 waves, (512,1) codegen.
// Epilogue: tanh per channel, then the w-weighted o-reduction as a SECOND MFMA
// (A2 = w-vector in C-layout slot order, B2 = bf16(t) packed from C regs).
// No tblW reads, no shfl; bias via proven fma(C,K2E,tblB).
__global__ __launch_bounds__(512, 1)
void k_sc(const unsigned int* __restrict__ Xbf,
          const float* __restrict__ W_att, const float* __restrict__ b_att,
          const float* __restrict__ w11, const float* __restrict__ w22,
          const float* __restrict__ w12,
          float* __restrict__ scG) {
  const int b = blockIdx.y;
  const int bx = blockIdx.x;           // 0..127
  const int tid = threadIdx.x;
  const int lane = tid & 63;
  const int w = tid >> 6;              // 0..7
  const int l31 = lane & 31;
  const int half = lane >> 5;

  __shared__ __align__(16) float tblB[64];          // K2E*b_att, C-reg order
  __shared__ __align__(16) unsigned int A2L[4][32]; // bf16-pair w in MFMA-2 A-slot order

  const unsigned int* __restrict__ Xb = Xbf + b * NN * 32;
  float* __restrict__ scb = scG + b * NN * NN;
  const float K2E = 2.8853900817779268f;

  if (tid < 64) {
    const int ot = tid >> 5, hf = (tid >> 4) & 1, r = tid & 15;
    const int o = ot * 32 + (r & 3) + 8 * (r >> 2) + 4 * hf;
    tblB[tid] = K2E * b_att[o];
  }
  if (tid >= 64 && tid < 320) {
    const int tt = tid - 64;           // 0..255
    const int comb = tt >> 6;          // it*2+jt
    const int idx = tt & 63;
    if (idx < 32) {
      // idx = ot<<4 | kg<<3 | hf<<2 | p ; slot e=2p,2p+1 of A2[k=hf*8+e]
      const int ot = (idx >> 4) & 1, kg = (idx >> 3) & 1, hf = (idx >> 2) & 1, pp = idx & 3;
      const int it_ = comb >> 1, jt_ = comb & 1;
      const float* wsl = it_ ? (jt_ ? w22 : w12) : (jt_ ? w12 : w11);
      const int e0 = 2 * pp, e1 = 2 * pp + 1;
      const int o0 = ot * 32 + kg * 16 + (e0 & 3) + 8 * (e0 >> 2) + 4 * hf;
      const int o1 = ot * 32 + kg * 16 + (e1 & 3) + 8 * (e1 >> 2) + 4 * hf;
      A2L[comb][idx] = cvtpk_bf16(wsl[o0], wsl[o1]);
    }
  }

  // W^T fragments in regs (32 VGPR, proven layout)
  BF8 Wp[2][4];
#pragma unroll
  for (int ot = 0; ot < 2; ++ot)
#pragma unroll
    for (int kt = 0; kt < 4; ++kt) {
      const int o = ot * 32 + l31;
#pragma unroll
      for (int pp = 0; pp < 4; ++pp) {
        const int d0 = kt * 16 + half * 8 + 2 * pp;
        Wp[ot][kt].u[pp] = cvtpk_bf16(W_att[d0 * DD + o], W_att[(d0 + 1) * DD + o]);
      }
    }

  __syncthreads();

  // job list (R12-proven): strips A rows {2bx,2bx+1} chunks [bx>>4,16),
  // B rows {510-2bx,511-2bx} chunks [(255-bx)>>4,16); 34 jobs/block.
  const int cminA = bx >> 4;
  const int n32A = 16 - cminA;
  const int rB = 510 - 2 * bx;
  const int cminB = (255 - bx) >> 4;
  const int njobs = 2 * (n32A + (16 - cminB));

#pragma unroll 1
  for (int jb = w; jb < njobs; jb += 8) {
    int row, c32;
    if (jb < 2 * n32A) { row = 2 * bx + (jb & 1); c32 = cminA + (jb >> 1); }
    else { const int tp = jb - 2 * n32A; row = rB + (tp & 1); c32 = cminB + (tp >> 1); }
    const int j0 = c32 * 32;
    const int comb = ((row >= NH) ? 2 : 0) | ((j0 >= NH) ? 1 : 0);

    // Bi = bf16(x_i ⊙ x_j), both operands from packed-bf16 global (R9/R11 numerics)
    BF8 Bi[4];
#pragma unroll
    for (int kt = 0; kt < 4; ++kt) {
      const uint4 xi = *reinterpret_cast<const uint4*>(Xb + row * 32 + kt * 8 + half * 4);
      const uint4 xj = *reinterpret_cast<const uint4*>(Xb + (j0 + l31) * 32 + kt * 8 + half * 4);
      Bi[kt].u[0] = cvtpk_bf16(bflo(xi.x) * bflo(xj.x), bfhi(xi.x) * bfhi(xj.x));
      Bi[kt].u[1] = cvtpk_bf16(bflo(xi.y) * bflo(xj.y), bfhi(xi.y) * bfhi(xj.y));
      Bi[kt].u[2] = cvtpk_bf16(bflo(xi.z) * bflo(xj.z), bfhi(xi.z) * bfhi(xj.z));
      Bi[kt].u[3] = cvtpk_bf16(bflo(xi.w) * bflo(xj.w), bfhi(xi.w) * bfhi(xj.w));
    }

    f32x16 C0 = {}, C1 = {};
#pragma unroll
    for (int kt = 0; kt < 4; ++kt) {
      C0 = __builtin_amdgcn_mfma_f32_32x32x16_bf16(Wp[0][kt].v, Bi[kt].v, C0, 0, 0, 0);
      C1 = __builtin_amdgcn_mfma_f32_32x32x16_bf16(Wp[1][kt].v, Bi[kt].v, C1, 0, 0, 0);
    }

    // epilogue: tanh per channel; weighted o-reduction via second MFMA
    f32x16 D2 = {};
    const int base = half * 16;
#pragma unroll
    for (int ot = 0; ot < 2; ++ot) {
      float tv[16];
#pragma unroll
      for (int r = 0; r < 16; ++r) {
        const float Cr = (ot == 0) ? C0[r] : C1[r];
        const float arg = fmaf(Cr, K2E, tblB[ot * 32 + base + r]);
        const float e = fast_exp2(arg);
        tv[r] = fmaf(-2.f, __builtin_amdgcn_rcpf(e + 1.f), 1.f);   // tanh
      }
      BF8 B2a, B2b;
#pragma unroll
      for (int pp = 0; pp < 4; ++pp) {
        B2a.u[pp] = cvtpk_bf16(tv[2 * pp], tv[2 * pp + 1]);        // kg0: regs 0..7
        B2b.u[pp] = cvtpk_bf16(tv[8 + 2 * pp], tv[9 + 2 * pp]);    // kg1: regs 8..15
      }
      BF8Q A2a, A2b;
      A2a.q = *reinterpret_cast<const uint4*>(&A2L[comb][ot * 16 + half * 4]);
      A2b.q = *reinterpret_cast<const uint4*>(&A2L[comb][ot * 16 + 8 + half * 4]);
      D2 = __builtin_amdgcn_mfma_f32_32x32x16_bf16(A2a.v, B2a.v, D2, 0, 0, 0);
      D2 = __builtin_amdgcn_mfma_f32_32x32x16_bf16(A2b.v, B2b.v, D2, 0, 0, 0);
    }
    const float pout = D2[0];            // all D2 rows equal (A2 rows identical)
    if (lane < 32) {
      const int j = j0 + l31;
      if (j >= row) {
        scb[row * NN + j] = pout;
        if (j > row) scb[j * NN + row] = pout;
      }
    }
  }
}

// K_REST: softmax + agg + y(selu) + logits + master (R12 passed verbatim).
__global__ __launch_bounds__(1024, 4)
void k_rest(const float* __restrict__ X, const float* __restrict__ scG,
            const float* __restrict__ W_attM, const float* __restrict__ b_attM,
            const float* __restrict__ wM,
            const float* __restrict__ W_pa, const float* __restrict__ b_pa,
            const float* __restrict__ W_po, const float* __restrict__ b_po,
            const float* __restrict__ gamma, const float* __restrict__ beta,
            float* __restrict__ master, float* __restrict__ logits,
            float* __restrict__ out) {
  const int b = blockIdx.y;
  const int i0 = blockIdx.x * 8;
  const int tid = threadIdx.x;
  const int lane = tid & 63;
  const int w = tid >> 6;        // 0..15

  __shared__ __align__(16) float Xlds[NN * DD];   // 128 KB
  __shared__ __align__(16) float scL[8 * NN];     // 16 KB
  __shared__ __align__(16) float red2[16][DD];    // 4 KB
  __shared__ __align__(16) float aggL[8][DD];     // 2 KB
  __shared__ __align__(16) float mastL[64];

  const float* __restrict__ Xb = X + b * NN * DD;

  // stage X[b] f32
  {
    const int c4 = (tid & 15) * 4;
    const int rh = tid >> 4;
#pragma unroll
    for (int it = 0; it < 8; ++it) {
      const int r = it * 64 + rh;
      *reinterpret_cast<float4*>(&Xlds[r * DD + c4]) =
          *reinterpret_cast<const float4*>(&Xb[r * DD + c4]);
    }
  }
  // stage scores
  {
    const int r8 = tid >> 7;
    const int c = (tid & 127) * 4;
    *reinterpret_cast<float4*>(&scL[r8 * NN + c]) =
        *reinterpret_cast<const float4*>(&scG[(b * NN + i0 + r8) * NN + c]);
  }
  __syncthreads();   // bar1

  // master mean
  {
    float s = 0.f;
    for (int r = w * 32; r < w * 32 + 32; ++r) s += Xlds[r * DD + lane];
    red2[w][lane] = s;
  }
  __syncthreads();   // bar2
  if (w == 0) {
    float s = 0.f;
#pragma unroll
    for (int k = 0; k < 16; ++k) s += red2[k][lane];
    s *= (1.f / 512.f);
    mastL[lane] = s;
    if (blockIdx.x == 0) master[b * DD + lane] = s;
  }

  // softmax: 2 waves per row
  const int row = w & 7, part = w >> 3;
  const int irow = i0 + row;
  float v[8];
#pragma unroll
  for (int k = 0; k < 8; ++k) v[k] = scL[row * NN + lane + 64 * k];
  __syncthreads();   // bar3b
  float mx = fmaxf(fmaxf(fmaxf(v[0], v[1]), fmaxf(v[2], v[3])),
                   fmaxf(fmaxf(v[4], v[5]), fmaxf(v[6], v[7])));
  mx = wred_max(mx);
  float ssum = 0.f;
#pragma unroll
  for (int k = 0; k < 8; ++k) { v[k] = __expf(v[k] - mx); ssum += v[k]; }
  ssum = wred_sum(ssum);
  const float inv = __builtin_amdgcn_rcpf(ssum);
#pragma unroll
  for (int k = 0; k < 4; ++k) {
    const int kk = part * 4 + k;
    scL[row * NN + lane + 64 * kk] = v[kk] * inv;
  }

  // agg partial over own j-half
  float a0 = 0.f, a1 = 0.f, a2 = 0.f, a3 = 0.f;
  const float* scr = &scL[row * NN + part * 256];
  const int xof = part * 256 * DD;
  for (int jj = 0; jj < 64; ++jj) {
    const float4 at = *reinterpret_cast<const float4*>(&scr[jj * 4]);
    a0 = fmaf(at.x, Xlds[xof + (jj * 4 + 0) * DD + lane], a0);
    a1 = fmaf(at.y, Xlds[xof + (jj * 4 + 1) * DD + lane], a1);
    a2 = fmaf(at.z, Xlds[xof + (jj * 4 + 2) * DD + lane], a2);
    a3 = fmaf(at.w, Xlds[xof + (jj * 4 + 3) * DD + lane], a3);
  }
  red2[w][lane] = (a0 + a1) + (a2 + a3);
  __syncthreads();   // bar4

  if (part == 0) {
    const float aggv = red2[w][lane] + red2[w + 8][lane];
    aggL[row][lane] = aggv;
    float y = b_pa[lane] + b_po[lane];
#pragma unroll 8
    for (int d = 0; d < DD; ++d) {
      y = fmaf(aggL[row][d], W_pa[d * DD + lane], y);
      y = fmaf(Xlds[irow * DD + d], W_po[d * DD + lane], y);
    }
    const float RSQ = 0.9999950000374997f;
    y = y * RSQ * gamma[lane] + beta[lane];
    const float SC_ = 1.0507009873554805f;
    const float AL = 1.6732632423543772f;
    y = (y > 0.f) ? (SC_ * y) : (SC_ * AL * (__expf(y) - 1.f));
    const int off = (irow < NH) ? ((b * NH + irow) * DD + lane)
                                : (BB * NH * DD + (b * NH + (irow - NH)) * DD + lane);
    out[off] = y;
  } else {
    float lg = b_attM[lane];
#pragma unroll 8
    for (int d = 0; d < DD; ++d)
      lg = fmaf(Xlds[irow * DD + d] * mastL[d], W_attM[d * DD + lane], lg);
    const float th = fast_tanh(lg);
    const float s = wred_sum(th * wM[lane]);
    if (lane == 0) logits[b * NN + irow] = s;
  }
}

// K4: softmax_n(logits) -> agg_m -> master_new (tail of out)
__global__ __launch_bounds__(256)
void k4_master_new(const float* __restrict__ X, const float* __restrict__ master,
                   const float* __restrict__ logits,
                   const float* __restrict__ W_paM, const float* __restrict__ b_paM,
                   const float* __restrict__ W_poM, const float* __restrict__ b_poM,
                   float* __restrict__ out) {
  const int b = blockIdx.x;
  const int tid = threadIdx.x;
  const int lane = tid & 63;
  const int q = tid >> 6;
  __shared__ float red[4][DD];
  __shared__ float r4[4];
  __shared__ float aggm_s[DD];
  __shared__ float mrow_s[DD];
  const float* lg = logits + b * NN;
  const float v0 = lg[tid];
  const float v1 = lg[tid + 256];
  float mx = wred_max(fmaxf(v0, v1));
  if (lane == 0) r4[q] = mx;
  __syncthreads();
  mx = fmaxf(fmaxf(r4[0], r4[1]), fmaxf(r4[2], r4[3]));
  float es = __expf(v0 - mx) + __expf(v1 - mx);
  es = wred_sum(es);
  __syncthreads();
  if (lane == 0) r4[q] = es;
  __syncthreads();
  const float S = r4[0] + r4[1] + r4[2] + r4[3];
  const float invS = 1.f / S;

  float acc = 0.f;
  for (int nn = q * 128; nn < q * 128 + 128; ++nn) {
    const float a = __expf(lg[nn] - mx);
    acc = fmaf(a, X[(b * NN + nn) * DD + lane], acc);
  }
  red[q][lane] = acc;
  __syncthreads();
  if (q == 0) {
    aggm_s[lane] =
        (red[0][lane] + red[1][lane] + red[2][lane] + red[3][lane]) * invS;
    mrow_s[lane] = master[b * DD + lane];
  }
  __syncthreads();
  float p = 0.f;
  for (int d = q * 16; d < q * 16 + 16; ++d) {
    p = fmaf(aggm_s[d], W_paM[d * DD + lane], p);
    p = fmaf(mrow_s[d], W_poM[d * DD + lane], p);
  }
  __syncthreads();
  red[q][lane] = p;
  __syncthreads();
  if (q == 0) {
    out[2 * BB * NH * DD + b * DD + lane] =
        red[0][lane] + red[1][lane] + red[2][lane] + red[3][lane] +
        b_paM[lane] + b_poM[lane];
  }
}

extern "C" void kernel_launch(void* const* d_in, const int* in_sizes, int n_in,
                              void* d_out, int out_size, void* d_ws, size_t ws_size,
                              hipStream_t stream) {
  const float* x1    = (const float*)d_in[0];
  const float* x2    = (const float*)d_in[1];
  const float* W_t1  = (const float*)d_in[2];
  const float* b_t1  = (const float*)d_in[3];
  const float* W_t2  = (const float*)d_in[4];
  const float* b_t2  = (const float*)d_in[5];
  const float* W_att = (const float*)d_in[6];
  const float* b_att = (const float*)d_in[7];
  const float* W_attM = (const float*)d_in[8];
  const float* b_attM = (const float*)d_in[9];
  const float* w11   = (const float*)d_in[10];
  const float* w22   = (const float*)d_in[11];
  const float* w12   = (const float*)d_in[12];
  const float* wM    = (const float*)d_in[13];
  const float* W_pa  = (const float*)d_in[14];
  const float* b_pa  = (const float*)d_in[15];
  const float* W_po  = (const float*)d_in[16];
  const float* b_po  = (const float*)d_in[17];
  const float* W_paM = (const float*)d_in[18];
  const float* b_paM = (const float*)d_in[19];
  const float* W_poM = (const float*)d_in[20];
  const float* b_poM = (const float*)d_in[21];
  const float* gamma = (const float*)d_in[22];
  const float* beta  = (const float*)d_in[23];

  float* ws     = (float*)d_ws;
  float* X      = ws;                         // 131072 floats
  float* master = ws + 131072;                // 256
  float* logits = ws + 131328;                // 2048
  float* scG    = ws + 133376;                // 1048576 floats (4 MB)
  unsigned int* Xbf = (unsigned int*)(ws + 133376 + 1048576);  // 65536 u32
  float* out    = (float*)d_out;

  k1_build_x<<<512, 256, 0, stream>>>(x1, x2, W_t1, b_t1, W_t2, b_t2, X, Xbf);
  k_sc<<<dim3(128, 4), 512, 0, stream>>>(Xbf, W_att, b_att, w11, w22, w12, scG);
  k_rest<<<dim3(64, 4), 1024, 0, stream>>>(X, scG, W_attM, b_attM, wM,
                                           W_pa, b_pa, W_po, b_po, gamma, beta,
                                           master, logits, out);
  k4_master_new<<<4, 256, 0, stream>>>(X, master, logits, W_paM, b_paM, W_poM, b_poM, out);
}

// Round 15
// 48.392 us; speedup vs baseline: 1.2226x; 1.0185x over previous
//
#include <hip/hip_runtime.h>

#define BB 4
#define NN 512
#define NH 256
#define DD 64

typedef __attribute__((ext_vector_type(8))) short bf16x8;
typedef __attribute__((ext_vector_type(16))) float f32x16;
union BF8 { bf16x8 v; unsigned int u[4]; };
union BF8Q { bf16x8 v; uint4 q; };

__device__ __forceinline__ float wred_sum(float v) {
  v += __shfl_xor(v, 32);
  v += __shfl_xor(v, 16);
  v += __shfl_xor(v, 8);
  v += __shfl_xor(v, 4);
  v += __shfl_xor(v, 2);
  v += __shfl_xor(v, 1);
  return v;
}

__device__ __forceinline__ float wred_max(float v) {
  v = fmaxf(v, __shfl_xor(v, 32));
  v = fmaxf(v, __shfl_xor(v, 16));
  v = fmaxf(v, __shfl_xor(v, 8));
  v = fmaxf(v, __shfl_xor(v, 4));
  v = fmaxf(v, __shfl_xor(v, 2));
  v = fmaxf(v, __shfl_xor(v, 1));
  return v;
}

__device__ __forceinline__ unsigned int cvtpk_bf16(float lo, float hi) {
  unsigned int r;
  asm("v_cvt_pk_bf16_f32 %0, %1, %2" : "=v"(r) : "v"(lo), "v"(hi));
  return r;
}

__device__ __forceinline__ float fast_exp2(float x) {
  float r;
  asm("v_exp_f32 %0, %1" : "=v"(r) : "v"(x));
  return r;
}

__device__ __forceinline__ float fast_tanh(float t) {
  t = fminf(15.f, fmaxf(-15.f, t));
  float z = __expf(2.f * t);
  return 1.f - 2.f * __builtin_amdgcn_rcpf(z + 1.f);
}

__device__ __forceinline__ float bflo(unsigned int u) { return __uint_as_float(u << 16); }
__device__ __forceinline__ float bfhi(unsigned int u) { return __uint_as_float(u & 0xffff0000u); }

// K1: x[b,n,:] = (n<256 ? x1@W_t1+b_t1 : x2@W_t2+b_t2); also bf16-packed Xbf.
__global__ __launch_bounds__(256)
void k1_build_x(const float* __restrict__ x1, const float* __restrict__ x2,
                const float* __restrict__ W_t1, const float* __restrict__ b_t1,
                const float* __restrict__ W_t2, const float* __restrict__ b_t2,
                float* __restrict__ X, unsigned int* __restrict__ XbfG) {
  const int tid = threadIdx.x;
  const int lane = tid & 63;
  const int rq = tid >> 6;
  const int r = blockIdx.x * 4 + rq;
  const int b = r >> 9;
  const int n = r & 511;
  const float* src; const float* W; const float* bias;
  if (n < NH) { src = x1 + (b * NH + n) * DD;        W = W_t1; bias = b_t1; }
  else        { src = x2 + (b * NH + (n - NH)) * DD; W = W_t2; bias = b_t2; }
  const float4* s4 = reinterpret_cast<const float4*>(src);
  float t0 = 0.f, t1 = 0.f, t2 = 0.f, t3 = 0.f;
#pragma unroll
  for (int c = 0; c < 16; ++c) {
    const float4 v = s4[c];
    t0 = fmaf(v.x, W[(4 * c + 0) * DD + lane], t0);
    t1 = fmaf(v.y, W[(4 * c + 1) * DD + lane], t1);
    t2 = fmaf(v.z, W[(4 * c + 2) * DD + lane], t2);
    t3 = fmaf(v.w, W[(4 * c + 3) * DD + lane], t3);
  }
  const float yv = ((t0 + t1) + (t2 + t3)) + bias[lane];
  X[r * DD + lane] = yv;
  const float nb = __shfl_down(yv, 1);      // partner d = lane+1 (same wave/row)
  if ((lane & 1) == 0) XbfG[r * 32 + (lane >> 1)] = cvtpk_bf16(yv, nb);
}

// K_SC: symmetric-triangle scores -> scG (R14 champion component, frozen).
__global__ __launch_bounds__(512, 1)
void k_sc(const unsigned int* __restrict__ Xbf,
          const float* __restrict__ W_att, const float* __restrict__ b_att,
          const float* __restrict__ w11, const float* __restrict__ w22,
          const float* __restrict__ w12,
          float* __restrict__ scG) {
  const int b = blockIdx.y;
  const int bx = blockIdx.x;           // 0..127
  const int tid = threadIdx.x;
  const int lane = tid & 63;
  const int w = tid >> 6;              // 0..7
  const int l31 = lane & 31;
  const int half = lane >> 5;

  __shared__ __align__(16) float tblB[64];          // K2E*b_att, C-reg order
  __shared__ __align__(16) unsigned int A2L[4][32]; // bf16-pair w in MFMA-2 A-slot order

  const unsigned int* __restrict__ Xb = Xbf + b * NN * 32;
  float* __restrict__ scb = scG + b * NN * NN;
  const float K2E = 2.8853900817779268f;

  if (tid < 64) {
    const int ot = tid >> 5, hf = (tid >> 4) & 1, r = tid & 15;
    const int o = ot * 32 + (r & 3) + 8 * (r >> 2) + 4 * hf;
    tblB[tid] = K2E * b_att[o];
  }
  if (tid >= 64 && tid < 320) {
    const int tt = tid - 64;           // 0..255
    const int comb = tt >> 6;          // it*2+jt
    const int idx = tt & 63;
    if (idx < 32) {
      const int ot = (idx >> 4) & 1, kg = (idx >> 3) & 1, hf = (idx >> 2) & 1, pp = idx & 3;
      const int it_ = comb >> 1, jt_ = comb & 1;
      const float* wsl = it_ ? (jt_ ? w22 : w12) : (jt_ ? w12 : w11);
      const int e0 = 2 * pp, e1 = 2 * pp + 1;
      const int o0 = ot * 32 + kg * 16 + (e0 & 3) + 8 * (e0 >> 2) + 4 * hf;
      const int o1 = ot * 32 + kg * 16 + (e1 & 3) + 8 * (e1 >> 2) + 4 * hf;
      A2L[comb][idx] = cvtpk_bf16(wsl[o0], wsl[o1]);
    }
  }

  BF8 Wp[2][4];
#pragma unroll
  for (int ot = 0; ot < 2; ++ot)
#pragma unroll
    for (int kt = 0; kt < 4; ++kt) {
      const int o = ot * 32 + l31;
#pragma unroll
      for (int pp = 0; pp < 4; ++pp) {
        const int d0 = kt * 16 + half * 8 + 2 * pp;
        Wp[ot][kt].u[pp] = cvtpk_bf16(W_att[d0 * DD + o], W_att[(d0 + 1) * DD + o]);
      }
    }

  __syncthreads();

  const int cminA = bx >> 4;
  const int n32A = 16 - cminA;
  const int rB = 510 - 2 * bx;
  const int cminB = (255 - bx) >> 4;
  const int njobs = 2 * (n32A + (16 - cminB));

#pragma unroll 1
  for (int jb = w; jb < njobs; jb += 8) {
    int row, c32;
    if (jb < 2 * n32A) { row = 2 * bx + (jb & 1); c32 = cminA + (jb >> 1); }
    else { const int tp = jb - 2 * n32A; row = rB + (tp & 1); c32 = cminB + (tp >> 1); }
    const int j0 = c32 * 32;
    const int comb = ((row >= NH) ? 2 : 0) | ((j0 >= NH) ? 1 : 0);

    BF8 Bi[4];
#pragma unroll
    for (int kt = 0; kt < 4; ++kt) {
      const uint4 xi = *reinterpret_cast<const uint4*>(Xb + row * 32 + kt * 8 + half * 4);
      const uint4 xj = *reinterpret_cast<const uint4*>(Xb + (j0 + l31) * 32 + kt * 8 + half * 4);
      Bi[kt].u[0] = cvtpk_bf16(bflo(xi.x) * bflo(xj.x), bfhi(xi.x) * bfhi(xj.x));
      Bi[kt].u[1] = cvtpk_bf16(bflo(xi.y) * bflo(xj.y), bfhi(xi.y) * bfhi(xj.y));
      Bi[kt].u[2] = cvtpk_bf16(bflo(xi.z) * bflo(xj.z), bfhi(xi.z) * bfhi(xj.z));
      Bi[kt].u[3] = cvtpk_bf16(bflo(xi.w) * bflo(xj.w), bfhi(xi.w) * bfhi(xj.w));
    }

    f32x16 C0 = {}, C1 = {};
#pragma unroll
    for (int kt = 0; kt < 4; ++kt) {
      C0 = __builtin_amdgcn_mfma_f32_32x32x16_bf16(Wp[0][kt].v, Bi[kt].v, C0, 0, 0, 0);
      C1 = __builtin_amdgcn_mfma_f32_32x32x16_bf16(Wp[1][kt].v, Bi[kt].v, C1, 0, 0, 0);
    }

    f32x16 D2 = {};
    const int base = half * 16;
#pragma unroll
    for (int ot = 0; ot < 2; ++ot) {
      float tv[16];
#pragma unroll
      for (int r = 0; r < 16; ++r) {
        const float Cr = (ot == 0) ? C0[r] : C1[r];
        const float arg = fmaf(Cr, K2E, tblB[ot * 32 + base + r]);
        const float e = fast_exp2(arg);
        tv[r] = fmaf(-2.f, __builtin_amdgcn_rcpf(e + 1.f), 1.f);   // tanh
      }
      BF8 B2a, B2b;
#pragma unroll
      for (int pp = 0; pp < 4; ++pp) {
        B2a.u[pp] = cvtpk_bf16(tv[2 * pp], tv[2 * pp + 1]);
        B2b.u[pp] = cvtpk_bf16(tv[8 + 2 * pp], tv[9 + 2 * pp]);
      }
      BF8Q A2a, A2b;
      A2a.q = *reinterpret_cast<const uint4*>(&A2L[comb][ot * 16 + half * 4]);
      A2b.q = *reinterpret_cast<const uint4*>(&A2L[comb][ot * 16 + 8 + half * 4]);
      D2 = __builtin_amdgcn_mfma_f32_32x32x16_bf16(A2a.v, B2a.v, D2, 0, 0, 0);
      D2 = __builtin_amdgcn_mfma_f32_32x32x16_bf16(A2b.v, B2b.v, D2, 0, 0, 0);
    }
    const float pout = D2[0];
    if (lane < 32) {
      const int j = j0 + l31;
      if (j >= row) {
        scb[row * NN + j] = pout;
        if (j > row) scb[j * NN + row] = pout;
      }
    }
  }
}

// K_REST: softmax + agg + y(selu) + logits + master — bf16-X overhaul.
// X staged as packed bf16 pairs (64 KB); agg reads d-pairs (one u32 covers
// 64 d across 32 lanes); projections unpack from 8 broadcast b128 reads.
__global__ __launch_bounds__(1024, 4)
void k_rest(const unsigned int* __restrict__ Xbf, const float* __restrict__ scG,
            const float* __restrict__ W_attM, const float* __restrict__ b_attM,
            const float* __restrict__ wM,
            const float* __restrict__ W_pa, const float* __restrict__ b_pa,
            const float* __restrict__ W_po, const float* __restrict__ b_po,
            const float* __restrict__ gamma, const float* __restrict__ beta,
            float* __restrict__ master, float* __restrict__ logits,
            float* __restrict__ out) {
  const int b = blockIdx.y;
  const int i0 = blockIdx.x * 8;
  const int tid = threadIdx.x;
  const int lane = tid & 63;
  const int w = tid >> 6;        // 0..15
  const int l31 = lane & 31;
  const int half = lane >> 5;

  __shared__ __align__(16) unsigned int XbfL[NN * 32];  // 64 KB bf16-pair tile
  __shared__ __align__(16) float scL[8 * NN];           // 16 KB
  __shared__ __align__(16) float red2[16][DD];          // 4 KB
  __shared__ __align__(16) float aggP[32][DD];          // 8 KB (row,part,half) partials
  __shared__ __align__(16) float aggL[8][DD];           // 2 KB
  __shared__ __align__(16) float mastL[64];

  const unsigned int* __restrict__ Xb = Xbf + b * NN * 32;

  // stage Xbf (16384 u32 = 4096 uint4; 1024 threads x 4)
  {
#pragma unroll
    for (int k = 0; k < 4; ++k)
      reinterpret_cast<uint4*>(XbfL)[tid + k * 1024] =
          reinterpret_cast<const uint4*>(Xb)[tid + k * 1024];
  }
  // stage scores
  {
    const int r8 = tid >> 7;
    const int c = (tid & 127) * 4;
    *reinterpret_cast<float4*>(&scL[r8 * NN + c]) =
        *reinterpret_cast<const float4*>(&scG[(b * NN + i0 + r8) * NN + c]);
  }
  __syncthreads();   // bar1

  // master mean from bf16 tile: lane <-> d-pair (halves redundant)
  {
    float se = 0.f, so = 0.f;
    for (int r = w * 32; r < w * 32 + 32; ++r) {
      const unsigned int u = XbfL[r * 32 + l31];
      se += bflo(u); so += bfhi(u);
    }
    if (half == 0) {
      float2 pr; pr.x = se; pr.y = so;
      *reinterpret_cast<float2*>(&red2[w][l31 * 2]) = pr;
    }
  }
  __syncthreads();   // bar2
  if (w == 0) {
    float s = 0.f;
#pragma unroll
    for (int k = 0; k < 16; ++k) s += red2[k][lane];
    s *= (1.f / 512.f);
    mastL[lane] = s;
    if (blockIdx.x == 0) master[b * DD + lane] = s;
  }

  // softmax: 2 waves per row (row = w&7, part = w>>3)
  const int row = w & 7, part = w >> 3;
  const int irow = i0 + row;
  float v[8];
#pragma unroll
  for (int k = 0; k < 8; ++k) v[k] = scL[row * NN + lane + 64 * k];
  __syncthreads();   // bar3b: all score reads done before att overwrite
  float mx = fmaxf(fmaxf(fmaxf(v[0], v[1]), fmaxf(v[2], v[3])),
                   fmaxf(fmaxf(v[4], v[5]), fmaxf(v[6], v[7])));
  mx = wred_max(mx);
  float ssum = 0.f;
#pragma unroll
  for (int k = 0; k < 8; ++k) { v[k] = __expf(v[k] - mx); ssum += v[k]; }
  ssum = wred_sum(ssum);
  const float inv = __builtin_amdgcn_rcpf(ssum);
#pragma unroll
  for (int k = 0; k < 4; ++k) {
    const int kk = part * 4 + k;
    scL[row * NN + lane + 64 * kk] = v[kk] * inv;
  }

  // agg from bf16 tile: lane <-> d-pair; half <-> 128-j subrange; 4 j per iter
  {
    float ae = 0.f, ao = 0.f;
    const int jb = part * 256 + half * 128;
#pragma unroll 4
    for (int it = 0; it < 32; ++it) {
      const int j = jb + it * 4;
      const float4 at = *reinterpret_cast<const float4*>(&scL[row * NN + j]);
      const unsigned int u0 = XbfL[(j + 0) * 32 + l31];
      const unsigned int u1 = XbfL[(j + 1) * 32 + l31];
      const unsigned int u2 = XbfL[(j + 2) * 32 + l31];
      const unsigned int u3 = XbfL[(j + 3) * 32 + l31];
      ae = fmaf(at.x, bflo(u0), ae); ao = fmaf(at.x, bfhi(u0), ao);
      ae = fmaf(at.y, bflo(u1), ae); ao = fmaf(at.y, bfhi(u1), ao);
      ae = fmaf(at.z, bflo(u2), ae); ao = fmaf(at.z, bfhi(u2), ao);
      ae = fmaf(at.w, bflo(u3), ae); ao = fmaf(at.w, bfhi(u3), ao);
    }
    float2 pr; pr.x = ae; pr.y = ao;
    *reinterpret_cast<float2*>(&aggP[row * 4 + part * 2 + half][l31 * 2]) = pr;
  }
  __syncthreads();   // bar4

  // x[irow] into regs (8 broadcast b128 reads), unpacked on use
  uint4 xr[8];
#pragma unroll
  for (int s = 0; s < 8; ++s)
    xr[s] = *reinterpret_cast<const uint4*>(&XbfL[irow * 32 + s * 4]);

  if (part == 0) {
    // y = selu(BN(agg@W_pa + x@W_po + biases))
    const float aggv = aggP[row * 4 + 0][lane] + aggP[row * 4 + 1][lane] +
                       aggP[row * 4 + 2][lane] + aggP[row * 4 + 3][lane];
    aggL[row][lane] = aggv;
    float y = b_pa[lane] + b_po[lane];
#pragma unroll
    for (int s = 0; s < 8; ++s) {
      const float xd[8] = {bflo(xr[s].x), bfhi(xr[s].x), bflo(xr[s].y), bfhi(xr[s].y),
                           bflo(xr[s].z), bfhi(xr[s].z), bflo(xr[s].w), bfhi(xr[s].w)};
      const float4 agA = *reinterpret_cast<const float4*>(&aggL[row][s * 8]);
      const float4 agB = *reinterpret_cast<const float4*>(&aggL[row][s * 8 + 4]);
      const float ad[8] = {agA.x, agA.y, agA.z, agA.w, agB.x, agB.y, agB.z, agB.w};
#pragma unroll
      for (int q = 0; q < 8; ++q) {
        const int d = s * 8 + q;
        y = fmaf(ad[q], W_pa[d * DD + lane], y);
        y = fmaf(xd[q], W_po[d * DD + lane], y);
      }
    }
    const float RSQ = 0.9999950000374997f;   // 1/sqrt(1+1e-5)
    y = y * RSQ * gamma[lane] + beta[lane];
    const float SC_ = 1.0507009873554805f;
    const float AL = 1.6732632423543772f;
    y = (y > 0.f) ? (SC_ * y) : (SC_ * AL * (__expf(y) - 1.f));
    const int off = (irow < NH) ? ((b * NH + irow) * DD + lane)
                                : (BB * NH * DD + (b * NH + (irow - NH)) * DD + lane);
    out[off] = y;
  } else {
    // logits[b,irow] = wM . tanh((x_i*master)@W_attM + b_attM)
    float lg = b_attM[lane];
#pragma unroll
    for (int s = 0; s < 8; ++s) {
      const float xd[8] = {bflo(xr[s].x), bfhi(xr[s].x), bflo(xr[s].y), bfhi(xr[s].y),
                           bflo(xr[s].z), bfhi(xr[s].z), bflo(xr[s].w), bfhi(xr[s].w)};
      const float4 mA = *reinterpret_cast<const float4*>(&mastL[s * 8]);
      const float4 mB = *reinterpret_cast<const float4*>(&mastL[s * 8 + 4]);
      const float md[8] = {mA.x, mA.y, mA.z, mA.w, mB.x, mB.y, mB.z, mB.w};
#pragma unroll
      for (int q = 0; q < 8; ++q) {
        const int d = s * 8 + q;
        lg = fmaf(xd[q] * md[q], W_attM[d * DD + lane], lg);
      }
    }
    const float th = fast_tanh(lg);
    const float s = wred_sum(th * wM[lane]);
    if (lane == 0) logits[b * NN + irow] = s;
  }
}

// K4: softmax_n(logits) -> agg_m -> master_new (tail of out)
__global__ __launch_bounds__(256)
void k4_master_new(const float* __restrict__ X, const float* __restrict__ master,
                   const float* __restrict__ logits,
                   const float* __restrict__ W_paM, const float* __restrict__ b_paM,
                   const float* __restrict__ W_poM, const float* __restrict__ b_poM,
                   float* __restrict__ out) {
  const int b = blockIdx.x;
  const int tid = threadIdx.x;
  const int lane = tid & 63;
  const int q = tid >> 6;
  __shared__ float red[4][DD];
  __shared__ float r4[4];
  __shared__ float aggm_s[DD];
  __shared__ float mrow_s[DD];
  const float* lg = logits + b * NN;
  const float v0 = lg[tid];
  const float v1 = lg[tid + 256];
  float mx = wred_max(fmaxf(v0, v1));
  if (lane == 0) r4[q] = mx;
  __syncthreads();
  mx = fmaxf(fmaxf(r4[0], r4[1]), fmaxf(r4[2], r4[3]));
  float es = __expf(v0 - mx) + __expf(v1 - mx);
  es = wred_sum(es);
  __syncthreads();
  if (lane == 0) r4[q] = es;
  __syncthreads();
  const float S = r4[0] + r4[1] + r4[2] + r4[3];
  const float invS = 1.f / S;

  float acc = 0.f;
  for (int nn = q * 128; nn < q * 128 + 128; ++nn) {
    const float a = __expf(lg[nn] - mx);
    acc = fmaf(a, X[(b * NN + nn) * DD + lane], acc);
  }
  red[q][lane] = acc;
  __syncthreads();
  if (q == 0) {
    aggm_s[lane] =
        (red[0][lane] + red[1][lane] + red[2][lane] + red[3][lane]) * invS;
    mrow_s[lane] = master[b * DD + lane];
  }
  __syncthreads();
  float p = 0.f;
  for (int d = q * 16; d < q * 16 + 16; ++d) {
    p = fmaf(aggm_s[d], W_paM[d * DD + lane], p);
    p = fmaf(mrow_s[d], W_poM[d * DD + lane], p);
  }
  __syncthreads();
  red[q][lane] = p;
  __syncthreads();
  if (q == 0) {
    out[2 * BB * NH * DD + b * DD + lane] =
        red[0][lane] + red[1][lane] + red[2][lane] + red[3][lane] +
        b_paM[lane] + b_poM[lane];
  }
}

extern "C" void kernel_launch(void* const* d_in, const int* in_sizes, int n_in,
                              void* d_out, int out_size, void* d_ws, size_t ws_size,
                              hipStream_t stream) {
  const float* x1    = (const float*)d_in[0];
  const float* x2    = (const float*)d_in[1];
  const float* W_t1  = (const float*)d_in[2];
  const float* b_t1  = (const float*)d_in[3];
  const float* W_t2  = (const float*)d_in[4];
  const float* b_t2  = (const float*)d_in[5];
  const float* W_att = (const float*)d_in[6];
  const float* b_att = (const float*)d_in[7];
  const float* W_attM = (const float*)d_in[8];
  const float* b_attM = (const float*)d_in[9];
  const float* w11   = (const float*)d_in[10];
  const float* w22   = (const float*)d_in[11];
  const float* w12   = (const float*)d_in[12];
  const float* wM    = (const float*)d_in[13];
  const float* W_pa  = (const float*)d_in[14];
  const float* b_pa  = (const float*)d_in[15];
  const float* W_po  = (const float*)d_in[16];
  const float* b_po  = (const float*)d_in[17];
  const float* W_paM = (const float*)d_in[18];
  const float* b_paM = (const float*)d_in[19];
  const float* W_poM = (const float*)d_in[20];
  const float* b_poM = (const float*)d_in[21];
  const float* gamma = (const float*)d_in[22];
  const float* beta  = (const float*)d_in[23];

  float* ws     = (float*)d_ws;
  float* X      = ws;                         // 131072 floats
  float* master = ws + 131072;                // 256
  float* logits = ws + 131328;                // 2048
  float* scG    = ws + 133376;                // 1048576 floats (4 MB)
  unsigned int* Xbf = (unsigned int*)(ws + 133376 + 1048576);  // 65536 u32
  float* out    = (float*)d_out;

  k1_build_x<<<512, 256, 0, stream>>>(x1, x2, W_t1, b_t1, W_t2, b_t2, X, Xbf);
  k_sc<<<dim3(128, 4), 512, 0, stream>>>(Xbf, W_att, b_att, w11, w22, w12, scG);
  k_rest<<<dim3(64, 4), 1024, 0, stream>>>(Xbf, scG, W_attM, b_attM, wM,
                                           W_pa, b_pa, W_po, b_po, gamma, beta,
                                           master, logits, out);
  k4_master_new<<<4, 256, 0, stream>>>(X, master, logits, W_paM, b_paM, W_poM, b_poM, out);
}